// Round 5
// baseline (468.424 us; speedup 1.0000x reference)
//
#include <hip/hip_runtime.h>
#include <stdint.h>

#define ALPHA 0.2f
#define EPSV  1e-5f

typedef unsigned short u16;
typedef unsigned int   u32;
typedef unsigned long long u64;
typedef __bf16 bf16x8 __attribute__((ext_vector_type(8)));
typedef __bf16 bf16x2 __attribute__((ext_vector_type(2)));
typedef float  f32x4  __attribute__((ext_vector_type(4)));

#define NB 8
#define NS 64
#define NN 256
#define NF 16
#define NH 16
#define NC 4096     // N*H
#define NK 12288    // NC*3
#define NP 512      // B*S (GEMM M / column count)
#define SROW 66     // padded rows per batch in Sp (1 zero + 64 + 1 zero)
#define BKT 32      // GEMM K per pipeline tile

__device__ __forceinline__ u16 f2b(float f){
  u32 u = __float_as_uint(f);
  u32 r = u + 0x7fffu + ((u>>16)&1u);   // round-nearest-even
  return (u16)(r>>16);
}
__device__ __forceinline__ void un2(u32 v, float& lo, float& hi){
  lo = __uint_as_float(v<<16); hi = __uint_as_float(v & 0xffff0000u);
}
__device__ __forceinline__ void gld16(void* lds, const void* g){
  __builtin_amdgcn_global_load_lds((const __attribute__((address_space(1))) u32*)g,
                                   (__attribute__((address_space(3))) u32*)lds, 16, 0, 0);
}
// 8 fp32 -> 8 bf16 (16B)
__device__ __forceinline__ uint4 cvt8(f32x4 a, f32x4 b){
  union { uint4 u; bf16x2 h[4]; } r;
  r.h[0] = (bf16x2){(__bf16)a[0], (__bf16)a[1]};
  r.h[1] = (bf16x2){(__bf16)a[2], (__bf16)a[3]};
  r.h[2] = (bf16x2){(__bf16)b[0], (__bf16)b[1]};
  r.h[3] = (bf16x2){(__bf16)b[2], (__bf16)b[3]};
  return r.u;
}

// ------- k_adj: adjacency -> bitmask, + zero Sp pad rows (64 blocks) ------
__global__ __launch_bounds__(256) void k_adj(const float* __restrict__ adj,
                                             u64* __restrict__ am,
                                             uint4* __restrict__ spz){
  int w = threadIdx.x>>6, l = threadIdx.x&63;
  int row = blockIdx.x*4 + w;
  #pragma unroll
  for(int g=0;g<4;g++){
    float v = adj[(size_t)row*NN + g*64 + l];
    u64 m = __ballot(v > 0.f);
    if(l==0) am[row*4+g] = m;
  }
  if(spz){
    int g = blockIdx.x*256 + threadIdx.x;    // 0..16383
    if(g < 8192){
      int r = g>>9;                          // pad row id 0..15
      int b = r>>1;
      size_t prow = (size_t)b*SROW + ((r&1) ? (SROW-1) : 0);
      spz[prow*512 + (g&511)] = (uint4){0,0,0,0};
    }
  }
}

// ---- k_cw2: conv_w [co][ci][3] fp32 -> Bw2 [kt][co][32] bf16 ------------
// kt = k*128 + (ci>>5): tap-major K' = k*4096+ci, tiled by 32 so the GEMM
// reads ONE contiguous 16-KB block per (K-tile, co-panel) instead of 256
// scattered 16-128B bursts at 24-49KB stride (the measured ~1.4 TB/s DRAM
// efficiency wall of R0-R4). Reads here are perfectly linear per co-row
// (each thread owns a contiguous 384-B window = 32 ci x 3 taps); writes are
// 64-B chunks lane-grouped by 4 co -> 256-B runs, adjacent blocks merge.
__global__ __launch_bounds__(512) void k_cw2(const float* __restrict__ cw,
                                             u16* __restrict__ Bw2){
  int t = threadIdx.x;
  int cs = t & 3;                 // co within group of 4 (write-run grouping)
  int cb = t >> 2;                // ci block 0..127
  int co = blockIdx.x*4 + cs;
  const f32x4* src = (const f32x4*)(cw + (size_t)co*NK + cb*96);
  f32x4 v[24];                    // 96 floats = 32 ci x 3 taps, contiguous
  #pragma unroll
  for(int i=0;i<24;i++) v[i] = src[i];
  #pragma unroll
  for(int k=0;k<3;k++){
    union { uint4 q[4]; u16 h[32]; } o;
    #pragma unroll
    for(int j=0;j<32;j++){
      int i = j*3 + k;            // compile-time register pick
      o.h[j] = f2b(v[i>>2][i&3]);
    }
    uint4* dst = (uint4*)(Bw2 + ((size_t)(k*128 + cb)*NC + co)*32);
    dst[0]=o.q[0]; dst[1]=o.q[1]; dst[2]=o.q[2]; dst[3]=o.q[3];
  }
}

// --- k_attn: per block bs, Wh + masked softmax + spatial -> Sp row (bf16)
__global__ __launch_bounds__(256) void k_attn(
    const float* __restrict__ x, const float* __restrict__ W,
    const float* __restrict__ a1, const float* __restrict__ a2,
    const u64* __restrict__ am, u16* __restrict__ Sp){
  __shared__ __align__(16) float Ws[NF][NH];
  __shared__ float a1s[NH], a2s[NH];
  __shared__ __align__(16) float Whs[NN][NH];
  __shared__ float f2s[NN];
  int t = threadIdx.x, bs = blockIdx.x;
  int b = bs>>6, s = bs&63;
  Ws[t>>4][t&15] = W[t];
  if(t<NH){ a1s[t]=a1[t]; a2s[t]=a2[t]; }
  u64 mg[4];
  #pragma unroll
  for(int g=0;g<4;g++) mg[g] = am[t*4+g];
  __syncthreads();

  const float* xp = x + ((size_t)bs*NN + t)*NF;
  float xr[16];
  #pragma unroll
  for(int g=0;g<4;g++) *(f32x4*)&xr[g*4] = ((const f32x4*)xp)[g];
  float wh[16];
  #pragma unroll
  for(int h=0;h<16;h++) wh[h]=0.f;
  #pragma unroll
  for(int f=0;f<16;f++){
    float xf = xr[f];
    #pragma unroll
    for(int h=0;h<16;h++) wh[h] = fmaf(xf, Ws[f][h], wh[h]);
  }
  float fi=0.f, s2=0.f;
  #pragma unroll
  for(int h=0;h<16;h++){ fi=fmaf(wh[h],a1s[h],fi); s2=fmaf(wh[h],a2s[h],s2); }
  #pragma unroll
  for(int g=0;g<4;g++) ((f32x4*)Whs[t])[g] = *(f32x4*)&wh[g*4];
  f2s[t] = s2;
  __syncthreads();

  float den = 0.f;
  f32x4 a0={0,0,0,0}, a1v={0,0,0,0}, a2v={0,0,0,0}, a3v={0,0,0,0};
  #pragma unroll
  for(int g=0;g<4;g++){
    u64 mm = mg[g];
    for(int jj=0;jj<64;jj++){
      int j = g*64+jj;
      float e = fi + f2s[j];
      e = e > 0.f ? e : ALPHA*e;
      float p = ((mm>>jj)&1ull) ? __expf(e) : 0.f;
      den += p;
      const f32x4* wr = (const f32x4*)Whs[j];
      a0 += wr[0]*p; a1v += wr[1]*p; a2v += wr[2]*p; a3v += wr[3]*p;
    }
  }
  float inv = 1.f/fmaxf(den, 1e-30f);
  f32x4 o0 = a0*inv, o1 = a1v*inv, o2 = a2v*inv, o3 = a3v*inv;

  uint4 w0 = cvt8(o0,o1), w1 = cvt8(o2,o3);
  uint4* op = (uint4*)(Sp + ((size_t)(b*SROW + s + 1))*NC) + t*2;
  op[0] = w0; op[1] = w1;
}

// ------- k_gemm: 256x256 tile, BKT=32, 4-buffer counted-vmcnt pipeline ---
// A row (col = b*64+s) = contiguous 12288-elem window at Sp[b][s][0]
// (tap-major im2col for free). B = Bw2 [kt][co][32]: per K-tile one
// CONTIGUOUS 16-KB block per co-panel -> full-efficiency HBM stream.
// Both operands via global_load_lds, granule-XOR swizzle (inverse on the
// per-lane global source; linear LDS dest; swizzled read offsets).
__global__ __launch_bounds__(512, 2) void k_gemm(
    const u16* __restrict__ Asp, const u16* __restrict__ Bw2,
    u16* __restrict__ yp, int kchunk){
  __shared__ __align__(16) u16 As[4][256*BKT];
  __shared__ __align__(16) u16 Bs[4][256*BKT];
  int t = threadIdx.x;

  int mI, nI, part;
  if(gridDim.y == 8){
    int lin = blockIdx.y*32 + blockIdx.x;   // hw dispatch-linear, 0..255
    int xcd = lin & 7, u = lin >> 3;
    nI = xcd*2 + (u&1); mI = (u>>1)&1; part = u>>2;
  } else {
    mI = blockIdx.x & 1; nI = blockIdx.x >> 1; part = blockIdx.y;
  }
  int m0 = mI*256, n0 = nI*256;
  int kbeg = part*kchunk;
  int NT = kchunk / BKT;
  int ktb = kbeg / BKT;                     // absolute K-tile base for B

  // staging: 2 A-chunks + 2 B-chunks (16B each) per thread per tile
  int c0 = t, c1 = 512 + t;
  int rA0 = c0>>2, rA1 = c1>>2;             // rows 0..127 / 128..255
  int g0 = (c0&3) ^ ((rA0>>1)&3);           // inverse-swizzled src granule
  int g1 = (c1&3) ^ ((rA1>>1)&3);
  int mr0 = m0 + rA0, mr1 = m0 + rA1;
  const u16* gaA0 = Asp + (size_t)((mr0>>6)*SROW + (mr0&63))*NC + kbeg + g0*8;
  const u16* gaA1 = Asp + (size_t)((mr1>>6)*SROW + (mr1&63))*NC + kbeg + g1*8;
  const u16* gbB0 = Bw2 + ((size_t)ktb*NC + n0 + rA0)*32 + g0*8;
  const u16* gbB1 = Bw2 + ((size_t)ktb*NC + n0 + rA1)*32 + g1*8;
  const size_t SB = (size_t)NC*32;          // B stride per K-tile (u16)
  int dA0 = c0*8, dA1 = c1*8;               // linear LDS dest (u16 units)

  int l = t & 63, w = t >> 6;
  int wr = w >> 2, wc = w & 3;              // 2M x 4N waves
  int q = l >> 4, r16 = l & 15;

  int offA[8], offB[4];                     // swizzled read offsets
  #pragma unroll
  for(int mt=0;mt<8;mt++){
    int row = wr*128 + mt*16 + r16;
    offA[mt] = row*BKT + ((q ^ ((row>>1)&3))*8);
  }
  #pragma unroll
  for(int nt=0;nt<4;nt++){
    int row = wc*64 + nt*16 + r16;
    offB[nt] = row*BKT + ((q ^ ((row>>1)&3))*8);
  }

  f32x4 acc[8][4];
  #pragma unroll
  for(int i=0;i<8;i++)
    #pragma unroll
    for(int j=0;j<4;j++) acc[i][j] = (f32x4){0,0,0,0};

  #define ISSUE(TT) { int bf=(TT)&3;                                          \
    size_t koA=(size_t)(TT)*BKT, koB=(size_t)(TT)*SB;                         \
    gld16(&As[bf][dA0], gaA0+koA); gld16(&As[bf][dA1], gaA1+koA);             \
    gld16(&Bs[bf][dA0], gbB0+koB); gld16(&Bs[bf][dA1], gbB1+koB); }

  // prologue: stage tiles 0,1,2 (12 loads in flight)
  ISSUE(0); ISSUE(1); ISSUE(2);

  #define COMPUTE(BUF)                                                        \
  {                                                                           \
    const u16* ab  = As[(BUF)];                                               \
    const u16* bb_ = Bs[(BUF)];                                               \
    bf16x8 af[8], bfr[4];                                                     \
    _Pragma("unroll")                                                         \
    for(int mt=0;mt<8;mt++) af[mt] = *(const bf16x8*)(ab + offA[mt]);         \
    _Pragma("unroll")                                                         \
    for(int nt=0;nt<4;nt++) bfr[nt] = *(const bf16x8*)(bb_ + offB[nt]);       \
    __builtin_amdgcn_s_setprio(1);                                            \
    _Pragma("unroll")                                                         \
    for(int mt=0;mt<8;mt++)                                                   \
      _Pragma("unroll")                                                       \
      for(int nt=0;nt<4;nt++)                                                 \
        acc[mt][nt] = __builtin_amdgcn_mfma_f32_16x16x32_bf16(                \
            af[mt], bfr[nt], acc[mt][nt], 0,0,0);                             \
    __builtin_amdgcn_s_setprio(0);                                            \
  }

  for(int T=0; T<NT-2; ++T){
    __builtin_amdgcn_sched_barrier(0);
    asm volatile("s_waitcnt vmcnt(8)" ::: "memory");   // retire tile T
    __builtin_amdgcn_s_barrier();                      // all waves: T landed
    __builtin_amdgcn_sched_barrier(0);
    if(T+3 < NT){ ISSUE(T+3); }
    COMPUTE(T&3);
  }
  __builtin_amdgcn_sched_barrier(0);
  asm volatile("s_waitcnt vmcnt(4)" ::: "memory");
  __builtin_amdgcn_s_barrier();
  __builtin_amdgcn_sched_barrier(0);
  COMPUTE((NT-2)&3);
  __builtin_amdgcn_sched_barrier(0);
  asm volatile("s_waitcnt vmcnt(0)" ::: "memory");
  __builtin_amdgcn_s_barrier();
  __builtin_amdgcn_sched_barrier(0);
  COMPUTE((NT-1)&3);
  #undef COMPUTE
  #undef ISSUE

  u16* op = yp + (size_t)part*NP*NC;
  #pragma unroll
  for(int mt=0;mt<8;mt++)
    #pragma unroll
    for(int nt=0;nt<4;nt++)
      #pragma unroll
      for(int rr=0;rr<4;rr++){
        int m = m0 + wr*128 + mt*16 + q*4 + rr;   // C/D: row = quad*4+reg
        int n = n0 + wc*64 + nt*16 + r16;         //      col = lane&15
        op[(size_t)m*NC + n] = f2b(acc[mt][nt][rr]);
      }
}

// ====================== fallback (old) path kernels ======================
__global__ __launch_bounds__(256) void k_attn_s(
    const float* __restrict__ x, const float* __restrict__ W,
    const float* __restrict__ a1, const float* __restrict__ a2,
    const u64* __restrict__ am, u16* __restrict__ Bt){
  __shared__ __align__(16) float Ws[NF][NH];
  __shared__ float a1s[NH], a2s[NH];
  __shared__ __align__(16) float Whs[NN][NH];
  __shared__ float f2s[NN];
  int t = threadIdx.x, bs = blockIdx.x;
  int b = bs>>6, s = bs&63;
  Ws[t>>4][t&15] = W[t];
  if(t<NH){ a1s[t]=a1[t]; a2s[t]=a2[t]; }
  u64 mg[4];
  #pragma unroll
  for(int g=0;g<4;g++) mg[g] = am[t*4+g];
  __syncthreads();

  const float* xp = x + ((size_t)bs*NN + t)*NF;
  float xr[16];
  #pragma unroll
  for(int g=0;g<4;g++) *(f32x4*)&xr[g*4] = ((const f32x4*)xp)[g];
  float wh[16];
  #pragma unroll
  for(int h=0;h<16;h++) wh[h]=0.f;
  #pragma unroll
  for(int f=0;f<16;f++){
    float xf = xr[f];
    #pragma unroll
    for(int h=0;h<16;h++) wh[h] = fmaf(xf, Ws[f][h], wh[h]);
  }
  float fi=0.f, s2=0.f;
  #pragma unroll
  for(int h=0;h<16;h++){ fi=fmaf(wh[h],a1s[h],fi); s2=fmaf(wh[h],a2s[h],s2); }
  #pragma unroll
  for(int g=0;g<4;g++) ((f32x4*)Whs[t])[g] = *(f32x4*)&wh[g*4];
  f2s[t] = s2;
  __syncthreads();

  float den = 0.f;
  f32x4 a0={0,0,0,0}, a1v={0,0,0,0}, a2v={0,0,0,0}, a3v={0,0,0,0};
  #pragma unroll
  for(int g=0;g<4;g++){
    u64 mm = mg[g];
    for(int jj=0;jj<64;jj++){
      int j = g*64+jj;
      float e = fi + f2s[j];
      e = e > 0.f ? e : ALPHA*e;
      float p = ((mm>>jj)&1ull) ? __expf(e) : 0.f;
      den += p;
      const f32x4* wr = (const f32x4*)Whs[j];
      a0 += wr[0]*p; a1v += wr[1]*p; a2v += wr[2]*p; a3v += wr[3]*p;
    }
  }
  float inv = 1.f/fmaxf(den, 1e-30f);
  float vals[16];
  *(f32x4*)&vals[0]  = a0*inv;  *(f32x4*)&vals[4]  = a1v*inv;
  *(f32x4*)&vals[8]  = a2v*inv; *(f32x4*)&vals[12] = a3v*inv;

  #pragma unroll
  for(int k=0;k<3;k++){
    int cs = s + 1 - k;
    if(cs >= 0 && cs < NS){
      size_t base = ((size_t)(b*NS+cs))*NK + (size_t)t*48 + k;
      #pragma unroll
      for(int h=0;h<16;h++) Bt[base + h*3] = f2b(vals[h]);
    }
  }
  if(s == 0){
    size_t base = ((size_t)(b*NS))*NK + (size_t)t*48;
    #pragma unroll
    for(int h=0;h<16;h++) Bt[base + h*3] = 0;
  }
  if(s == NS-1){
    size_t base = ((size_t)(b*NS+NS-1))*NK + (size_t)t*48 + 2;
    #pragma unroll
    for(int h=0;h<16;h++) Bt[base + h*3] = 0;
  }
}

__global__ __launch_bounds__(256) void k_gemm_f(
    const u16* __restrict__ Abt, const float* __restrict__ Bwf,
    u16* __restrict__ yp, int kchunk){
  __shared__ __align__(16) u16 As0[128*32];
  __shared__ __align__(16) u16 As1[128*32];
  __shared__ __align__(16) u16 Bs0[128*32];
  __shared__ __align__(16) u16 Bs1[128*32];
  int t = threadIdx.x;
  int id = blockIdx.x;
  int xr_ = id & 7, q0 = id >> 3;
  int mI = q0 & 3, nhi = q0 >> 2;
  int m0 = mI*128, n0 = (nhi*8 + xr_)*128;
  int kbeg = blockIdx.y*kchunk;
  f32x4 acc[4][4];
  #pragma unroll
  for(int i=0;i<4;i++)
    #pragma unroll
    for(int j=0;j<4;j++) acc[i][j] = (f32x4){0,0,0,0};

  int l = t&63, w = t>>6;
  int wm = (w&1)*64, wn = (w>>1)*64;
  int q = l>>4, r16 = l&15;

  int c0 = t, c1 = t+256;
  const u16*   ga0 = Abt + (size_t)(m0 + (c0>>2))*NK + (c0&3)*8;
  const u16*   ga1 = Abt + (size_t)(m0 + (c1>>2))*NK + (c1&3)*8;
  const float* gb0 = Bwf + (size_t)(n0 + (c0>>2))*NK + (c0&3)*8;
  const float* gb1 = Bwf + (size_t)(n0 + (c1>>2))*NK + (c1&3)*8;
  u16 *la00 = As0 + c0*8, *la01 = As0 + c1*8;
  u16 *la10 = As1 + c0*8, *la11 = As1 + c1*8;
  u16 *lb00 = Bs0 + c0*8, *lb01 = Bs0 + c1*8;
  u16 *lb10 = Bs1 + c0*8, *lb11 = Bs1 + c1*8;

  for(int kk=0; kk<kchunk; kk+=64){
    int k0 = kbeg + kk;
    f32x4 v00a = *(const f32x4*)(gb0 + k0);
    f32x4 v00b = *(const f32x4*)(gb0 + k0 + 4);
    f32x4 v01a = *(const f32x4*)(gb1 + k0);
    f32x4 v01b = *(const f32x4*)(gb1 + k0 + 4);
    f32x4 v10a = *(const f32x4*)(gb0 + k0 + 32);
    f32x4 v10b = *(const f32x4*)(gb0 + k0 + 36);
    f32x4 v11a = *(const f32x4*)(gb1 + k0 + 32);
    f32x4 v11b = *(const f32x4*)(gb1 + k0 + 36);
    uint4 w00 = cvt8(v00a, v00b);
    uint4 w01 = cvt8(v01a, v01b);
    uint4 w10 = cvt8(v10a, v10b);
    uint4 w11 = cvt8(v11a, v11b);
    __syncthreads();
    gld16(la00, ga0 + k0);      gld16(la01, ga1 + k0);
    gld16(la10, ga0 + k0 + 32); gld16(la11, ga1 + k0 + 32);
    *(uint4*)lb00 = w00; *(uint4*)lb01 = w01;
    *(uint4*)lb10 = w10; *(uint4*)lb11 = w11;
    __syncthreads();
    {
      bf16x8 af[4], bfr[4];
      #pragma unroll
      for(int mt=0;mt<4;mt++) af[mt]  = *(const bf16x8*)(As0 + (wm+mt*16+r16)*32 + q*8);
      #pragma unroll
      for(int nt=0;nt<4;nt++) bfr[nt] = *(const bf16x8*)(Bs0 + (wn+nt*16+r16)*32 + q*8);
      #pragma unroll
      for(int mt=0;mt<4;mt++)
        #pragma unroll
        for(int nt=0;nt<4;nt++)
          acc[mt][nt] = __builtin_amdgcn_mfma_f32_16x16x32_bf16(af[mt], bfr[nt], acc[mt][nt], 0,0,0);
    }
    {
      bf16x8 af[4], bfr[4];
      #pragma unroll
      for(int mt=0;mt<4;mt++) af[mt]  = *(const bf16x8*)(As1 + (wm+mt*16+r16)*32 + q*8);
      #pragma unroll
      for(int nt=0;nt<4;nt++) bfr[nt] = *(const bf16x8*)(Bs1 + (wn+nt*16+r16)*32 + q*8);
      #pragma unroll
      for(int mt=0;mt<4;mt++)
        #pragma unroll
        for(int nt=0;nt<4;nt++)
          acc[mt][nt] = __builtin_amdgcn_mfma_f32_16x16x32_bf16(af[mt], bfr[nt], acc[mt][nt], 0,0,0);
    }
  }
  u16* op = yp + (size_t)blockIdx.y*NP*NC;
  #pragma unroll
  for(int mt=0;mt<4;mt++)
    #pragma unroll
    for(int nt=0;nt<4;nt++)
      #pragma unroll
      for(int rr=0;rr<4;rr++){
        int m = m0 + wm + mt*16 + q*4 + rr;
        int n = n0 + wn + nt*16 + r16;
        op[(size_t)m*NC + n] = f2b(acc[mt][nt][rr]);
      }
}

// ------ k_post: sum split-K (bf16), conv_b+BN+relu+residual+LayerNorm ----
__global__ __launch_bounds__(256) void k_post(
    const u16* __restrict__ yp, int nparts,
    const float* __restrict__ x,
    const float* __restrict__ cb, const float* __restrict__ bg,
    const float* __restrict__ bb, const float* __restrict__ bm,
    const float* __restrict__ bv, const float* __restrict__ lg,
    const float* __restrict__ lb, float* __restrict__ out){
  int n = threadIdx.x, bs = blockIdx.x;
  float v[16];
  #pragma unroll
  for(int h=0;h<16;h++) v[h]=0.f;
  for(int p=0;p<nparts;p++){
    const u16* pp = yp + (size_t)p*NP*NC + (size_t)bs*NC + n*16;
    uint4 u0 = ((const uint4*)pp)[0];
    uint4 u1 = ((const uint4*)pp)[1];
    float lo, hi;
    un2(u0.x,lo,hi); v[0]+=lo;  v[1]+=hi;
    un2(u0.y,lo,hi); v[2]+=lo;  v[3]+=hi;
    un2(u0.z,lo,hi); v[4]+=lo;  v[5]+=hi;
    un2(u0.w,lo,hi); v[6]+=lo;  v[7]+=hi;
    un2(u1.x,lo,hi); v[8]+=lo;  v[9]+=hi;
    un2(u1.y,lo,hi); v[10]+=lo; v[11]+=hi;
    un2(u1.z,lo,hi); v[12]+=lo; v[13]+=hi;
    un2(u1.w,lo,hi); v[14]+=lo; v[15]+=hi;
  }
  const float* xp = x + ((size_t)bs*NN + n)*NH;
  float xr[16];
  #pragma unroll
  for(int g=0;g<4;g++) *(f32x4*)&xr[g*4] = ((const f32x4*)xp)[g];

  float mu = 0.f;
  #pragma unroll
  for(int h=0;h<16;h++){
    int co = n*16 + h;
    float t1 = v[h] + cb[co];
    t1 = (t1 - bm[co]) * (1.f/sqrtf(bv[co] + EPSV));
    t1 = t1 * bg[co] + bb[co];
    t1 = fmaxf(t1, 0.f);
    t1 += xr[h];
    v[h] = t1; mu += t1;
  }
  mu *= (1.f/16.f);
  float var = 0.f;
  #pragma unroll
  for(int h=0;h<16;h++){ float d = v[h]-mu; var = fmaf(d,d,var); }
  var *= (1.f/16.f);
  float rs = 1.f/sqrtf(var + EPSV);
  float* op = out + ((size_t)bs*NN + n)*NH;
  #pragma unroll
  for(int h=0;h<16;h++) op[h] = (v[h]-mu)*rs*lg[h] + lb[h];
}

extern "C" void kernel_launch(void* const* d_in, const int* in_sizes, int n_in,
                              void* d_out, int out_size, void* d_ws, size_t ws_size,
                              hipStream_t stream){
  const float* x   = (const float*)d_in[0];
  const float* adj = (const float*)d_in[1];
  const float* W   = (const float*)d_in[2];
  const float* a1  = (const float*)d_in[3];
  const float* a2  = (const float*)d_in[4];
  const float* cw  = (const float*)d_in[5];
  const float* cb  = (const float*)d_in[6];
  const float* bg  = (const float*)d_in[7];
  const float* bb  = (const float*)d_in[8];
  const float* bm  = (const float*)d_in[9];
  const float* bv  = (const float*)d_in[10];
  const float* lg  = (const float*)d_in[11];
  const float* lb  = (const float*)d_in[12];
  float* out = (float*)d_out;

  char* ws = (char*)d_ws;
  const size_t ypb = (size_t)NP*NC*2;                 // 4 MB per split part

  // ---- new path layout: am | Sp | Bw2 | yp  (~137 MB for P=8) ----
  const size_t SP_OFF  = 8192;                        // after am (8 KB)
  const size_t SP_SZ   = (size_t)NB*SROW*NC*2;        // 4.33 MB padded spatial
  const size_t BW_OFF  = SP_OFF + SP_SZ;
  const size_t BW_SZ   = (size_t)NC*NK*2;             // 100.7 MB K-tiled bf16 weights
  const size_t YP_OFF2 = BW_OFF + BW_SZ;

  u64* am = (u64*)ws;

  int P2 = 0;
  if(ws_size >= YP_OFF2 + 8*ypb)      P2 = 8;
  else if(ws_size >= YP_OFF2 + 4*ypb) P2 = 4;
  else if(ws_size >= YP_OFF2 + 2*ypb) P2 = 2;
  else if(ws_size >= YP_OFF2 + 1*ypb) P2 = 1;

  if(P2){
    u16* Sp  = (u16*)(ws + SP_OFF);
    u16* Bw2 = (u16*)(ws + BW_OFF);
    u16* yp  = (u16*)(ws + YP_OFF2);
    hipLaunchKernelGGL(k_adj,  dim3(64),      dim3(256), 0, stream, adj, am, (uint4*)Sp);
    hipLaunchKernelGGL(k_cw2,  dim3(NC/4),    dim3(512), 0, stream, cw, Bw2);
    hipLaunchKernelGGL(k_attn, dim3(NP),      dim3(256), 0, stream, x,W,a1,a2,am,Sp);
    hipLaunchKernelGGL(k_gemm, dim3(32,P2),   dim3(512), 0, stream, Sp, Bw2, yp, NK/P2);
    hipLaunchKernelGGL(k_post, dim3(NP),      dim3(256), 0, stream, yp,P2,x,cb,bg,bb,bm,bv,lg,lb,out);
  } else {
    // fallback: previous verified path (scatter im2col + fused-cvt GEMM)
    const size_t BT_OFF = 8192;
    const size_t YP_OFF = BT_OFF + (size_t)NP*NK*2;
    int P = 1;
    if(ws_size >= YP_OFF + 8*ypb)      P = 8;
    else if(ws_size >= YP_OFF + 4*ypb) P = 4;
    else if(ws_size >= YP_OFF + 2*ypb) P = 2;
    u16* Bt = (u16*)(ws + BT_OFF);
    u16* yp = (u16*)(ws + YP_OFF);
    hipLaunchKernelGGL(k_adj,    dim3(64),     dim3(256), 0, stream, adj, am, (uint4*)0);
    hipLaunchKernelGGL(k_attn_s, dim3(NP),     dim3(256), 0, stream, x,W,a1,a2,am,Bt);
    hipLaunchKernelGGL(k_gemm_f, dim3(128,P),  dim3(256), 0, stream, Bt, cw, yp, NK/P);
    hipLaunchKernelGGL(k_post,   dim3(NP),     dim3(256), 0, stream, yp,P,x,cb,bg,bb,bm,bv,lg,lb,out);
  }
}